// Round 3
// baseline (199.323 us; speedup 1.0000x reference)
//
#include <hip/hip_runtime.h>
#include <stdint.h>

#define B 8
#define F 8192
#define C 256
#define K 4
#define P (F / 4)     // 2048
#define CAP 16        // max tracked incoming collapsed faces per target
#define NB 4096       // linear bins over per-batch [lo, hi]
#define NFL ((B * F) / 256)   // kFL block count = 256

// Monotone, deterministic linear bin — computed identically in kHT and kFL.
__device__ __forceinline__ int binOf(float v, float lo, float scale) {
    int bin = (int)((v - lo) * scale);
    return bin < 0 ? 0 : (bin > NB - 1 ? NB - 1 : bin);
}

// ---------------------------------------------------------------------------
// kW: one wave per face — gather K=4 ring rows, mean, L2 norm -> w.
// Lane 0 zeroes cnt/flag. Block->batch swizzle: blockIdx&7 = batch, so each
// XCD's L2 serves ONE batch's 8 MB feat slice instead of all 64 MB.
// (R7 lesson: NO histogram atomics here.)
// ---------------------------------------------------------------------------
__global__ __launch_bounds__(256) void kW(const float* __restrict__ feat,
                                          const int* __restrict__ ring,
                                          float* __restrict__ w,
                                          int* __restrict__ cnt,
                                          int* __restrict__ flag) {
    const int b     = blockIdx.x & 7;                       // batch == XCD
    const int inner = blockIdx.x >> 3;                      // [0, 2048)
    const int wid   = b * F + inner * 4 + (threadIdx.x >> 6);
    const int lane  = threadIdx.x & 63;

    const int rbase = wid * K;
    const int r0 = ring[rbase + 0], r1 = ring[rbase + 1];
    const int r2 = ring[rbase + 2], r3 = ring[rbase + 3];
    const float4* f4 = (const float4*)feat;
    const size_t base = (size_t)b * F;
    const int    CW   = C / 4;
    const float4 v0 = f4[(base + r0) * CW + lane];
    const float4 v1 = f4[(base + r1) * CW + lane];
    const float4 v2 = f4[(base + r2) * CW + lane];
    const float4 v3 = f4[(base + r3) * CW + lane];

    float4 a;
    a.x = (v0.x + v1.x) + (v2.x + v3.x);
    a.y = (v0.y + v1.y) + (v2.y + v3.y);
    a.z = (v0.z + v1.z) + (v2.z + v3.z);
    a.w = (v0.w + v1.w) + (v2.w + v3.w);
    float s = (a.x * a.x + a.y * a.y + a.z * a.z + a.w * a.w) * 0.0625f;
#pragma unroll
    for (int off = 32; off > 0; off >>= 1) s += __shfl_down(s, off, 64);
    if (lane == 0) {
        w[wid]    = sqrtf(s);
        cnt[wid]  = 0;
        flag[wid] = 0;
    }
}

// ---------------------------------------------------------------------------
// kHT: ONE block (1024 thr = 16 waves) per batch — min/max + 4096-bin
// histogram + scan -> threshold bin T, rank R. Rewritten with WAVE
// primitives: shfl_xor min/max reduce + shfl_up scan -> 6 barriers total
// (old version: ~44). Math identical: same binOf, same lo/hi bit publish.
// ---------------------------------------------------------------------------
__global__ __launch_bounds__(1024) void kHT(const float* __restrict__ w,
                                            int* __restrict__ tbin,
                                            int* __restrict__ trank,
                                            int* __restrict__ ccnt,
                                            unsigned int* __restrict__ lsb,
                                            int* __restrict__ done) {
    __shared__ int h[NB];                                   // 16 KiB
    __shared__ unsigned int redmn[16], redmx[16];
    __shared__ int wsum[16], woff[16];
    __shared__ unsigned int slo, shi;
    const int b = blockIdx.x, t = threadIdx.x;
    const int lane = t & 63, wv = t >> 6;

    // load 8 values/thread, coalesced; per-thread min/max (w>=0: bit-monotone)
    float val[8];
    unsigned int mn = 0xFFFFFFFFu, mx = 0u;
#pragma unroll
    for (int k = 0; k < 8; ++k) {
        val[k] = w[b * F + t + k * 1024];
        const unsigned int u = __float_as_uint(val[k]);
        mn = mn < u ? mn : u;
        mx = mx > u ? mx : u;
    }
    // wave-level min/max reduce
#pragma unroll
    for (int off = 32; off > 0; off >>= 1) {
        const unsigned int o1 = __shfl_xor(mn, off, 64); mn = mn < o1 ? mn : o1;
        const unsigned int o2 = __shfl_xor(mx, off, 64); mx = mx > o2 ? mx : o2;
    }
    if (lane == 0) { redmn[wv] = mn; redmx[wv] = mx; }
    for (int i = t; i < NB; i += 1024) h[i] = 0;            // zero hist (pre-barrier)
    __syncthreads();                                        // [1]
    if (t == 0) {
        unsigned int a = redmn[0], c = redmx[0];
        for (int i = 1; i < 16; ++i) {
            a = a < redmn[i] ? a : redmn[i];
            c = c > redmx[i] ? c : redmx[i];
        }
        slo = a; shi = c;
    }
    __syncthreads();                                        // [2]
    const unsigned int lob = slo, hib = shi;
    const float lo    = __uint_as_float(lob);
    const float hi    = __uint_as_float(hib);
    const float scale = (float)(NB - 2) / fmaxf(hi - lo, 1e-30f);

    // histogram (max ~7 hits/bin -> negligible LDS-atomic contention)
#pragma unroll
    for (int k = 0; k < 8; ++k) atomicAdd(&h[binOf(val[k], lo, scale)], 1);
    __syncthreads();                                        // [3]

    // per-thread sum of 4 bins -> wave inclusive scan -> cross-wave offsets
    int s = 0;
#pragma unroll
    for (int i = 0; i < 4; ++i) s += h[t * 4 + i];
    int incl = s;
#pragma unroll
    for (int off = 1; off < 64; off <<= 1) {
        const int u = __shfl_up(incl, off, 64);
        if (lane >= off) incl += u;
    }
    if (lane == 63) wsum[wv] = incl;
    __syncthreads();                                        // [4]
    if (t < 16) {
        const int v = wsum[t];
        int iv = v;
#pragma unroll
        for (int off = 1; off < 16; off <<= 1) {
            const int u = __shfl_up(iv, off, 64);
            if (t >= off) iv += u;
        }
        woff[t] = iv - v;                                   // exclusive wave offset
    }
    __syncthreads();                                        // [5]
    const int inclT = incl + woff[wv];
    const int exclT = inclT - s;
    if (P - 1 >= exclT && P - 1 < inclT) {                  // exactly one thread
        int c = exclT;
#pragma unroll
        for (int i = 0; i < 4; ++i) {
            const int bin = t * 4 + i;
            const int hv  = h[bin];
            if (P - 1 < c + hv) { tbin[b] = bin; trank[b] = P - c; break; }
            c += hv;
        }
    }
    if (t == 0) {
        ccnt[b]        = 0;
        lsb[b * 2 + 0] = lob;
        lsb[b * 2 + 1] = hib;
        if (b == 0) *done = 0;
    }
}

// ---------------------------------------------------------------------------
// kFL: 256 blocks (full width preserved — round-2 lesson: FL atomics need
// the whole GPU). bin < T -> flag + push; bin == T -> LDS-compact candidates.
// NEW: last-block-done ticket fuses the old kSel in (device-scope fences;
// 256th block ranks the ~7 boundary candidates of all 8 batches).
// ---------------------------------------------------------------------------
__global__ __launch_bounds__(256) void kFL(const float* __restrict__ w,
                                           const int* __restrict__ adj,
                                           const unsigned int* __restrict__ lsb,
                                           const int* __restrict__ tbin,
                                           const int* __restrict__ trank,
                                           int* __restrict__ flag,
                                           int* __restrict__ cnt,
                                           int* __restrict__ srcs,
                                           unsigned long long* __restrict__ cand,
                                           int* __restrict__ ccnt,
                                           int* __restrict__ done) {
    __shared__ unsigned long long lc[256];
    __shared__ int lcnt;
    __shared__ int lbase;
    __shared__ int ticket;
    if (threadIdx.x == 0) lcnt = 0;
    __syncthreads();

    const int t = blockIdx.x * 256 + threadIdx.x;           // [0, B*F)
    const int b = t >> 13;                                  // block spans one batch
    const float lo    = __uint_as_float(lsb[b * 2 + 0]);
    const float hi    = __uint_as_float(lsb[b * 2 + 1]);
    const float scale = (float)(NB - 2) / fmaxf(hi - lo, 1e-30f);

    const float v = w[t];
    const int bin = binOf(v, lo, scale);
    const int T = tbin[b];
    if (bin < T) {
        flag[t] = 1;
#pragma unroll
        for (int j = 0; j < 3; ++j) {
            const int n    = adj[(size_t)t * 3 + j];
            const int tgt  = b * F + n;
            const int slot = atomicAdd(&cnt[tgt], 1);
            if (slot < CAP) srcs[(size_t)tgt * CAP + slot] = t;
        }
    } else if (bin == T) {
        const int pos = atomicAdd(&lcnt, 1);                // LDS atomic: cheap
        lc[pos] = ((unsigned long long)__float_as_uint(v) << 32) | (uint32_t)(t & (F - 1));
    }
    __syncthreads();
    if (threadIdx.x == 0 && lcnt > 0)
        lbase = atomicAdd(&ccnt[b], lcnt);                  // 1 contended op/block
    __syncthreads();
    const int m = lcnt;
    for (int i = threadIdx.x; i < m; i += 256)
        cand[(size_t)b * F + lbase + i] = lc[i];

    // ---- last-block-done: fused Sel phase (replaces the kSel dispatch) ----
    __threadfence();                                        // release cand/ccnt
    __syncthreads();
    if (threadIdx.x == 0) ticket = atomicAdd(done, 1);
    __syncthreads();
    if (ticket == NFL - 1) {                                // last block only
        __threadfence();                                    // acquire
        for (int bb = 0; bb < B; ++bb) {
            const int n0 = ccnt[bb];
            const int n  = n0 < F ? n0 : F;
            const int R  = trank[bb];
            for (int i = threadIdx.x; i < n; i += 256) {
                const unsigned long long my = cand[(size_t)bb * F + i];
                int rank = 0;
                for (int j = 0; j < n; ++j)
                    rank += (cand[(size_t)bb * F + j] < my) ? 1 : 0;
                if (rank < R) {
                    const int tt = bb * F + (int)(uint32_t)my;
                    flag[tt] = 1;
#pragma unroll
                    for (int j = 0; j < 3; ++j) {
                        const int nb   = adj[(size_t)tt * 3 + j];
                        const int tgt  = bb * F + nb;
                        const int slot = atomicAdd(&cnt[tgt], 1);
                        if (slot < CAP) srcs[(size_t)tgt * CAP + slot] = tt;
                    }
                }
            }
        }
    }
}

// ---------------------------------------------------------------------------
// kG: one wave per face — fused merge + normalize + erase, same batch<->XCD
// swizzle as kW (incoming-src gathers are batch-local). (unchanged)
// ---------------------------------------------------------------------------
__global__ __launch_bounds__(256) void kG(const float* __restrict__ feat,
                                          const int* __restrict__ cnt,
                                          const int* __restrict__ flag,
                                          const int* __restrict__ srcs,
                                          float* __restrict__ out) {
    const int b     = blockIdx.x & 7;                       // batch == XCD
    const int inner = blockIdx.x >> 3;
    const int wid   = b * F + inner * 4 + (threadIdx.x >> 6);
    const int lane  = threadIdx.x & 63;
    float4* drow = (float4*)(out + (size_t)wid * C);

    if (flag[wid]) {                                        // wave-uniform branch
        drow[lane] = make_float4(0.f, 0.f, 0.f, 0.f);
        return;
    }
    const int m  = cnt[wid];
    const int mm = m < CAP ? m : CAP;

    const int sidx = (lane < CAP) ? srcs[(size_t)wid * CAP + lane] : 0;

    float4 acc = ((const float4*)(feat + (size_t)wid * C))[lane];
    const float inv3 = 1.0f / 3.0f;
    for (int i = 0; i < mm; ++i) {
        const int s = __shfl(sidx, i, 64);
        const float4 v = ((const float4*)(feat + (size_t)s * C))[lane];
        acc.x += v.x * inv3; acc.y += v.y * inv3;
        acc.z += v.z * inv3; acc.w += v.w * inv3;
    }
    const float inv = 1.0f / (1.0f + (float)m);
    acc.x *= inv; acc.y *= inv; acc.z *= inv; acc.w *= inv;
    drow[lane] = acc;
}

extern "C" void kernel_launch(void* const* d_in, const int* in_sizes, int n_in,
                              void* d_out, int out_size, void* d_ws, size_t ws_size,
                              hipStream_t stream) {
    const float* feat = (const float*)d_in[0];
    const int*   adj  = (const int*)d_in[1];
    const int*   ring = (const int*)d_in[2];
    float* out = (float*)d_out;

    // ws layout: cand (8B-aligned) | w | cnt | flag | srcs | ccnt | tbin |
    //            trank | lsb | done
    unsigned long long* cand = (unsigned long long*)d_ws;   // B*F (512 KiB)
    float* w     = (float*)(cand + B * F);                  // B*F
    int*   cnt   = (int*)(w + B * F);                       // B*F
    int*   flag  = cnt + B * F;                             // B*F
    int*   srcs  = flag + B * F;                            // B*F*CAP (4 MiB)
    int*   ccnt  = srcs + (size_t)B * F * CAP;              // B
    int*   tbin  = ccnt + B;                                // B
    int*   trank = tbin + B;                                // B
    unsigned int* lsb = (unsigned int*)(trank + B);         // 2*B
    int*   done  = (int*)(lsb + 2 * B);                     // 1

    kW  <<<(B * F) / 4, 256, 0, stream>>>(feat, ring, w, cnt, flag);
    kHT <<<B, 1024, 0, stream>>>(w, tbin, trank, ccnt, lsb, done);
    kFL <<<NFL, 256, 0, stream>>>(w, adj, lsb, tbin, trank, flag, cnt, srcs, cand, ccnt, done);
    kG  <<<(B * F) / 4, 256, 0, stream>>>(feat, cnt, flag, srcs, out);
}

// Round 4
// 160.503 us; speedup vs baseline: 1.2419x; 1.2419x over previous
//
#include <hip/hip_runtime.h>
#include <stdint.h>

#define B 8
#define F 8192
#define C 256
#define K 4
#define P (F / 4)     // 2048
#define CAP 16        // max tracked incoming collapsed faces per target
#define NB 4096       // linear bins over per-batch [lo, hi]
#define BF (B * F)

// Monotone, deterministic linear bin — computed identically in kHT and kFL.
__device__ __forceinline__ int binOf(float v, float lo, float scale) {
    int bin = (int)((v - lo) * scale);
    return bin < 0 ? 0 : (bin > NB - 1 ? NB - 1 : bin);
}

// Sum of the 4 per-quarter partial norms. IDENTICAL expression in kHT and
// kFL (no -ffast-math -> no reassociation) => bit-deterministic agreement.
__device__ __forceinline__ float loadS(const float* __restrict__ wq, int i) {
    return (wq[i] + wq[BF + i]) + (wq[2 * BF + i] + wq[3 * BF + i]);
}

// ---------------------------------------------------------------------------
// kW: channel-QUARTERED gather. norm^2 is separable over channels, so each
// (batch, quarter) pass touches only 512 B/row = 2 MB per XCD — L2-resident
// (vs 8 MB before: 2x L2 -> row re-reads came from L3/HBM at ~6.4 TB/s).
// Quarter lives in the HIGH bits of blockIdx so an XCD finishes quarter q
// of its batch before q+1 (temporal locality). 16 lanes x float4 = one
// quarter-row; 4 faces/wave; ranking value is norm^2 (sqrt dropped: monotone).
// ---------------------------------------------------------------------------
__global__ __launch_bounds__(256) void kW(const float* __restrict__ feat,
                                          const int* __restrict__ ring,
                                          float* __restrict__ wq,   // [4][B*F]
                                          int* __restrict__ cnt,
                                          int* __restrict__ flag) {
    const int b     = blockIdx.x & 7;                     // batch == XCD
    const int tmp   = blockIdx.x >> 3;
    const int inner = tmp & 511;                          // [0, 512)
    const int q     = tmp >> 9;                           // quarter [0, 4)
    const int wv    = threadIdx.x >> 6;                   // wave [0, 4)
    const int lane  = threadIdx.x & 63;
    const int grp   = lane >> 4;                          // face group [0, 4)
    const int sub   = lane & 15;

    const int fid = inner * 16 + wv * 4 + grp;            // [0, F)
    const int wid = b * F + fid;

    const int rbase = wid * K;
    const int r0 = ring[rbase + 0], r1 = ring[rbase + 1];
    const int r2 = ring[rbase + 2], r3 = ring[rbase + 3];
    const float4* f4 = (const float4*)feat;
    const size_t base = (size_t)b * F;
    const int    CW   = C / 4;                            // 64 float4/row
    const int    off  = q * 16 + sub;                     // float4 idx in row
    const float4 v0 = f4[(base + r0) * CW + off];
    const float4 v1 = f4[(base + r1) * CW + off];
    const float4 v2 = f4[(base + r2) * CW + off];
    const float4 v3 = f4[(base + r3) * CW + off];

    float4 a;
    a.x = (v0.x + v1.x) + (v2.x + v3.x);
    a.y = (v0.y + v1.y) + (v2.y + v3.y);
    a.z = (v0.z + v1.z) + (v2.z + v3.z);
    a.w = (v0.w + v1.w) + (v2.w + v3.w);
    float s = (a.x * a.x + a.y * a.y + a.z * a.z + a.w * a.w) * 0.0625f;
    // reduce within each 16-lane group (decreasing offsets stay in-group
    // for the lanes that feed sub==0)
#pragma unroll
    for (int o = 8; o > 0; o >>= 1) s += __shfl_down(s, o, 64);
    if (sub == 0) {
        wq[q * BF + wid] = s;
        if (q == 0) { cnt[wid] = 0; flag[wid] = 0; }
    }
}

// ---------------------------------------------------------------------------
// kHT: ONE block (1024 thr = 16 waves) per batch — min/max + 4096-bin
// histogram + scan -> threshold bin T, rank R. Wave-primitive version
// (6 barriers vs ~44): shfl_xor min/max reduce + shfl_up scan.
// Validated in round 3. Reads the quartered partials via loadS.
// ---------------------------------------------------------------------------
__global__ __launch_bounds__(1024) void kHT(const float* __restrict__ wq,
                                            int* __restrict__ tbin,
                                            int* __restrict__ trank,
                                            int* __restrict__ ccnt,
                                            unsigned int* __restrict__ lsb) {
    __shared__ int h[NB];                                   // 16 KiB
    __shared__ unsigned int redmn[16], redmx[16];
    __shared__ int wsum[16], woff[16];
    __shared__ unsigned int slo, shi;
    const int b = blockIdx.x, t = threadIdx.x;
    const int lane = t & 63, wv = t >> 6;

    // load 8 values/thread, coalesced; per-thread min/max (s>=0: bit-monotone)
    float val[8];
    unsigned int mn = 0xFFFFFFFFu, mx = 0u;
#pragma unroll
    for (int k = 0; k < 8; ++k) {
        val[k] = loadS(wq, b * F + t + k * 1024);
        const unsigned int u = __float_as_uint(val[k]);
        mn = mn < u ? mn : u;
        mx = mx > u ? mx : u;
    }
#pragma unroll
    for (int off = 32; off > 0; off >>= 1) {
        const unsigned int o1 = __shfl_xor(mn, off, 64); mn = mn < o1 ? mn : o1;
        const unsigned int o2 = __shfl_xor(mx, off, 64); mx = mx > o2 ? mx : o2;
    }
    if (lane == 0) { redmn[wv] = mn; redmx[wv] = mx; }
    for (int i = t; i < NB; i += 1024) h[i] = 0;            // zero hist
    __syncthreads();                                        // [1]
    if (t == 0) {
        unsigned int a = redmn[0], c = redmx[0];
        for (int i = 1; i < 16; ++i) {
            a = a < redmn[i] ? a : redmn[i];
            c = c > redmx[i] ? c : redmx[i];
        }
        slo = a; shi = c;
    }
    __syncthreads();                                        // [2]
    const unsigned int lob = slo, hib = shi;
    const float lo    = __uint_as_float(lob);
    const float hi    = __uint_as_float(hib);
    const float scale = (float)(NB - 2) / fmaxf(hi - lo, 1e-30f);

#pragma unroll
    for (int k = 0; k < 8; ++k) atomicAdd(&h[binOf(val[k], lo, scale)], 1);
    __syncthreads();                                        // [3]

    int s = 0;
#pragma unroll
    for (int i = 0; i < 4; ++i) s += h[t * 4 + i];
    int incl = s;
#pragma unroll
    for (int off = 1; off < 64; off <<= 1) {
        const int u = __shfl_up(incl, off, 64);
        if (lane >= off) incl += u;
    }
    if (lane == 63) wsum[wv] = incl;
    __syncthreads();                                        // [4]
    if (t < 16) {
        const int v = wsum[t];
        int iv = v;
#pragma unroll
        for (int off = 1; off < 16; off <<= 1) {
            const int u = __shfl_up(iv, off, 64);
            if (t >= off) iv += u;
        }
        woff[t] = iv - v;                                   // exclusive offset
    }
    __syncthreads();                                        // [5]
    const int inclT = incl + woff[wv];
    const int exclT = inclT - s;
    if (P - 1 >= exclT && P - 1 < inclT) {                  // exactly one thread
        int c = exclT;
#pragma unroll
        for (int i = 0; i < 4; ++i) {
            const int bin = t * 4 + i;
            const int hv  = h[bin];
            if (P - 1 < c + hv) { tbin[b] = bin; trank[b] = P - c; break; }
            c += hv;
        }
    }
    if (t == 0) {
        ccnt[b]        = 0;
        lsb[b * 2 + 0] = lob;
        lsb[b * 2 + 1] = hib;
    }
}

// ---------------------------------------------------------------------------
// kFL: 256 blocks, full GPU width (round-2 lesson: FL atomics need width;
// round-3 lesson: NO last-block ticket/threadfence — it cost 40 µs).
// bin < T -> flag + push; bin == T -> LDS-compact candidates, one ccnt
// atomic per block.
// ---------------------------------------------------------------------------
__global__ __launch_bounds__(256) void kFL(const float* __restrict__ wq,
                                           const int* __restrict__ adj,
                                           const unsigned int* __restrict__ lsb,
                                           const int* __restrict__ tbin,
                                           int* __restrict__ flag,
                                           int* __restrict__ cnt,
                                           int* __restrict__ srcs,
                                           unsigned long long* __restrict__ cand,
                                           int* __restrict__ ccnt) {
    __shared__ unsigned long long lc[256];
    __shared__ int lcnt;
    __shared__ int lbase;
    if (threadIdx.x == 0) lcnt = 0;
    __syncthreads();

    const int t = blockIdx.x * 256 + threadIdx.x;           // [0, B*F)
    const int b = t >> 13;                                  // block spans one batch
    const float lo    = __uint_as_float(lsb[b * 2 + 0]);
    const float hi    = __uint_as_float(lsb[b * 2 + 1]);
    const float scale = (float)(NB - 2) / fmaxf(hi - lo, 1e-30f);

    const float v = loadS(wq, t);
    const int bin = binOf(v, lo, scale);
    const int T = tbin[b];
    if (bin < T) {
        flag[t] = 1;
#pragma unroll
        for (int j = 0; j < 3; ++j) {
            const int n    = adj[(size_t)t * 3 + j];
            const int tgt  = b * F + n;
            const int slot = atomicAdd(&cnt[tgt], 1);
            if (slot < CAP) srcs[(size_t)tgt * CAP + slot] = t;
        }
    } else if (bin == T) {
        const int pos = atomicAdd(&lcnt, 1);                // LDS atomic: cheap
        lc[pos] = ((unsigned long long)__float_as_uint(v) << 32) | (uint32_t)(t & (F - 1));
    }
    __syncthreads();
    if (threadIdx.x == 0 && lcnt > 0)
        lbase = atomicAdd(&ccnt[b], lcnt);                  // 1 contended op/block
    __syncthreads();
    const int m = lcnt;
    for (int i = threadIdx.x; i < m; i += 256)
        cand[(size_t)b * F + lbase + i] = lc[i];
}

// ---------------------------------------------------------------------------
// kSel: per batch — exact rank of boundary candidates by O(n^2) counting
// (keys distinct via idx bits; s>=0 so bit order == float order). n ~ 7.
// ---------------------------------------------------------------------------
__global__ __launch_bounds__(1024) void kSel(const int* __restrict__ ccnt,
                                             const int* __restrict__ trank,
                                             const unsigned long long* __restrict__ cand,
                                             const int* __restrict__ adj,
                                             int* __restrict__ flag,
                                             int* __restrict__ cnt,
                                             int* __restrict__ srcs) {
    __shared__ unsigned long long keys[F];                  // 64 KiB
    const int b = blockIdx.x;
    const int n = ccnt[b];
    const int R = trank[b];
    for (int i = threadIdx.x; i < n; i += 1024)
        keys[i] = cand[(size_t)b * F + i];
    __syncthreads();
    for (int i = threadIdx.x; i < n; i += 1024) {
        const unsigned long long my = keys[i];
        int rank = 0;
        for (int j = 0; j < n; ++j) rank += (keys[j] < my) ? 1 : 0;
        if (rank < R) {
            const int t = b * F + (int)(uint32_t)my;
            flag[t] = 1;
#pragma unroll
            for (int j = 0; j < 3; ++j) {
                const int nb   = adj[(size_t)t * 3 + j];
                const int tgt  = b * F + nb;
                const int slot = atomicAdd(&cnt[tgt], 1);
                if (slot < CAP) srcs[(size_t)tgt * CAP + slot] = t;
            }
        }
    }
}

// ---------------------------------------------------------------------------
// kG: one wave per face — fused merge + normalize + erase, same batch<->XCD
// swizzle as kW (incoming-src gathers are batch-local). (unchanged)
// ---------------------------------------------------------------------------
__global__ __launch_bounds__(256) void kG(const float* __restrict__ feat,
                                          const int* __restrict__ cnt,
                                          const int* __restrict__ flag,
                                          const int* __restrict__ srcs,
                                          float* __restrict__ out) {
    const int b     = blockIdx.x & 7;                       // batch == XCD
    const int inner = blockIdx.x >> 3;
    const int wid   = b * F + inner * 4 + (threadIdx.x >> 6);
    const int lane  = threadIdx.x & 63;
    float4* drow = (float4*)(out + (size_t)wid * C);

    if (flag[wid]) {                                        // wave-uniform branch
        drow[lane] = make_float4(0.f, 0.f, 0.f, 0.f);
        return;
    }
    const int m  = cnt[wid];
    const int mm = m < CAP ? m : CAP;

    const int sidx = (lane < CAP) ? srcs[(size_t)wid * CAP + lane] : 0;

    float4 acc = ((const float4*)(feat + (size_t)wid * C))[lane];
    const float inv3 = 1.0f / 3.0f;
    for (int i = 0; i < mm; ++i) {
        const int s = __shfl(sidx, i, 64);
        const float4 v = ((const float4*)(feat + (size_t)s * C))[lane];
        acc.x += v.x * inv3; acc.y += v.y * inv3;
        acc.z += v.z * inv3; acc.w += v.w * inv3;
    }
    const float inv = 1.0f / (1.0f + (float)m);
    acc.x *= inv; acc.y *= inv; acc.z *= inv; acc.w *= inv;
    drow[lane] = acc;
}

extern "C" void kernel_launch(void* const* d_in, const int* in_sizes, int n_in,
                              void* d_out, int out_size, void* d_ws, size_t ws_size,
                              hipStream_t stream) {
    const float* feat = (const float*)d_in[0];
    const int*   adj  = (const int*)d_in[1];
    const int*   ring = (const int*)d_in[2];
    float* out = (float*)d_out;

    // ws layout: cand (8B-aligned) | wq[4] | cnt | flag | srcs | ccnt | tbin |
    //            trank | lsb
    unsigned long long* cand = (unsigned long long*)d_ws;   // B*F (512 KiB)
    float* wq    = (float*)(cand + BF);                     // 4*B*F (1 MiB)
    int*   cnt   = (int*)(wq + 4 * BF);                     // B*F
    int*   flag  = cnt + BF;                                // B*F
    int*   srcs  = flag + BF;                               // B*F*CAP (4 MiB)
    int*   ccnt  = srcs + (size_t)BF * CAP;                 // B
    int*   tbin  = ccnt + B;                                // B
    int*   trank = tbin + B;                                // B
    unsigned int* lsb = (unsigned int*)(trank + B);         // 2*B

    kW  <<<B * 4 * (F / 16), 256, 0, stream>>>(feat, ring, wq, cnt, flag);
    kHT <<<B, 1024, 0, stream>>>(wq, tbin, trank, ccnt, lsb);
    kFL <<<BF / 256, 256, 0, stream>>>(wq, adj, lsb, tbin, flag, cnt, srcs, cand, ccnt);
    kSel<<<B, 1024, 0, stream>>>(ccnt, trank, cand, adj, flag, cnt, srcs);
    kG  <<<BF / 4, 256, 0, stream>>>(feat, cnt, flag, srcs, out);
}

// Round 5
// 156.494 us; speedup vs baseline: 1.2737x; 1.0256x over previous
//
#include <hip/hip_runtime.h>
#include <stdint.h>

#define B 8
#define F 8192
#define C 256
#define K 4
#define P (F / 4)     // 2048
#define CAP 16        // max tracked incoming collapsed faces per target
#define NB 4096       // linear bins over per-batch [lo, hi]
#define BF (B * F)
#define CCAP 4096     // kHT LDS candidate capacity (bin==T population ~ O(10))

typedef float f32x4 __attribute__((ext_vector_type(4)));

// Monotone, deterministic linear bin — computed identically in kHT and kFL.
__device__ __forceinline__ int binOf(float v, float lo, float scale) {
    int bin = (int)((v - lo) * scale);
    return bin < 0 ? 0 : (bin > NB - 1 ? NB - 1 : bin);
}

// ---------------------------------------------------------------------------
// kW: one wave per face — gather K=4 ring rows, mean, L2 norm^2 -> w.
// (sqrt dropped: monotone, ranking unchanged — validated round 4.)
// Lane 0 zeroes cnt/flag. Block->batch swizzle: blockIdx&7 = batch.
// Round-4 lesson: channel-quartering for L2 fit was NEUTRAL — reverted.
// ---------------------------------------------------------------------------
__global__ __launch_bounds__(256) void kW(const float* __restrict__ feat,
                                          const int* __restrict__ ring,
                                          float* __restrict__ w,
                                          int* __restrict__ cnt,
                                          int* __restrict__ flag) {
    const int b     = blockIdx.x & 7;                       // batch == XCD
    const int inner = blockIdx.x >> 3;                      // [0, 2048)
    const int wid   = b * F + inner * 4 + (threadIdx.x >> 6);
    const int lane  = threadIdx.x & 63;

    const int rbase = wid * K;
    const int r0 = ring[rbase + 0], r1 = ring[rbase + 1];
    const int r2 = ring[rbase + 2], r3 = ring[rbase + 3];
    const float4* f4 = (const float4*)feat;
    const size_t base = (size_t)b * F;
    const int    CW   = C / 4;
    const float4 v0 = f4[(base + r0) * CW + lane];
    const float4 v1 = f4[(base + r1) * CW + lane];
    const float4 v2 = f4[(base + r2) * CW + lane];
    const float4 v3 = f4[(base + r3) * CW + lane];

    float4 a;
    a.x = (v0.x + v1.x) + (v2.x + v3.x);
    a.y = (v0.y + v1.y) + (v2.y + v3.y);
    a.z = (v0.z + v1.z) + (v2.z + v3.z);
    a.w = (v0.w + v1.w) + (v2.w + v3.w);
    float s = (a.x * a.x + a.y * a.y + a.z * a.z + a.w * a.w) * 0.0625f;
#pragma unroll
    for (int off = 32; off > 0; off >>= 1) s += __shfl_down(s, off, 64);
    if (lane == 0) {
        w[wid]    = s;                                      // norm^2 (monotone)
        cnt[wid]  = 0;
        flag[wid] = 0;
    }
}

// ---------------------------------------------------------------------------
// kHT: ONE block (1024 thr = 16 waves) per batch. Wave-primitive min/max +
// 4096-bin histogram + shfl scan -> threshold bin T, rank R  (validated
// round 3/4), PLUS fused boundary selection (old kSel): re-bin the 8
// register-resident values, LDS-compact bin==T candidates (~O(10)),
// O(n^2) exact rank, rank<R -> flag + push. Kills the kSel dispatch and
// kFL's whole candidate path (cand/ccnt gone).
// ---------------------------------------------------------------------------
__global__ __launch_bounds__(1024) void kHT(const float* __restrict__ w,
                                            const int* __restrict__ adj,
                                            int* __restrict__ tbin,
                                            unsigned int* __restrict__ lsb,
                                            int* __restrict__ flag,
                                            int* __restrict__ cnt,
                                            int* __restrict__ srcs) {
    __shared__ int h[NB];                                   // 16 KiB
    __shared__ unsigned long long carr[CCAP];               // 32 KiB
    __shared__ unsigned int redmn[16], redmx[16];
    __shared__ int wsum[16], woff[16];
    __shared__ unsigned int slo, shi;
    __shared__ int sT, sR, scnt;
    const int b = blockIdx.x, t = threadIdx.x;
    const int lane = t & 63, wv = t >> 6;

    if (t == 0) scnt = 0;

    // load 8 values/thread, coalesced; per-thread min/max (w>=0: bit-monotone)
    float val[8];
    unsigned int mn = 0xFFFFFFFFu, mx = 0u;
#pragma unroll
    for (int k = 0; k < 8; ++k) {
        val[k] = w[b * F + t + k * 1024];
        const unsigned int u = __float_as_uint(val[k]);
        mn = mn < u ? mn : u;
        mx = mx > u ? mx : u;
    }
#pragma unroll
    for (int off = 32; off > 0; off >>= 1) {
        const unsigned int o1 = __shfl_xor(mn, off, 64); mn = mn < o1 ? mn : o1;
        const unsigned int o2 = __shfl_xor(mx, off, 64); mx = mx > o2 ? mx : o2;
    }
    if (lane == 0) { redmn[wv] = mn; redmx[wv] = mx; }
    for (int i = t; i < NB; i += 1024) h[i] = 0;            // zero hist
    __syncthreads();                                        // [1]
    if (t == 0) {
        unsigned int a = redmn[0], c = redmx[0];
        for (int i = 1; i < 16; ++i) {
            a = a < redmn[i] ? a : redmn[i];
            c = c > redmx[i] ? c : redmx[i];
        }
        slo = a; shi = c;
    }
    __syncthreads();                                        // [2]
    const unsigned int lob = slo, hib = shi;
    const float lo    = __uint_as_float(lob);
    const float hi    = __uint_as_float(hib);
    const float scale = (float)(NB - 2) / fmaxf(hi - lo, 1e-30f);

#pragma unroll
    for (int k = 0; k < 8; ++k) atomicAdd(&h[binOf(val[k], lo, scale)], 1);
    __syncthreads();                                        // [3]

    int s = 0;
#pragma unroll
    for (int i = 0; i < 4; ++i) s += h[t * 4 + i];
    int incl = s;
#pragma unroll
    for (int off = 1; off < 64; off <<= 1) {
        const int u = __shfl_up(incl, off, 64);
        if (lane >= off) incl += u;
    }
    if (lane == 63) wsum[wv] = incl;
    __syncthreads();                                        // [4]
    if (t < 16) {
        const int v = wsum[t];
        int iv = v;
#pragma unroll
        for (int off = 1; off < 16; off <<= 1) {
            const int u = __shfl_up(iv, off, 64);
            if (t >= off) iv += u;
        }
        woff[t] = iv - v;                                   // exclusive offset
    }
    __syncthreads();                                        // [5]
    const int inclT = incl + woff[wv];
    const int exclT = inclT - s;
    if (P - 1 >= exclT && P - 1 < inclT) {                  // exactly one thread
        int c = exclT;
#pragma unroll
        for (int i = 0; i < 4; ++i) {
            const int bin = t * 4 + i;
            const int hv  = h[bin];
            if (P - 1 < c + hv) { sT = bin; sR = P - c; break; }
            c += hv;
        }
    }
    if (t == 0) {
        lsb[b * 2 + 0] = lob;
        lsb[b * 2 + 1] = hib;
    }
    __syncthreads();                                        // [6]
    const int T = sT, R = sR;
    if (t == 0) tbin[b] = T;                                // for kFL

    // ---- fused Sel: compact bin==T candidates from registers ----
#pragma unroll
    for (int k = 0; k < 8; ++k) {
        if (binOf(val[k], lo, scale) == T) {
            const int pos = atomicAdd(&scnt, 1);            // LDS atomic
            if (pos < CCAP)
                carr[pos] = ((unsigned long long)__float_as_uint(val[k]) << 32) |
                            (uint32_t)(t + k * 1024);       // idx in [0,F)
        }
    }
    __syncthreads();                                        // [7]
    const int n = scnt < CCAP ? scnt : CCAP;
    for (int i = t; i < n; i += 1024) {
        const unsigned long long my = carr[i];
        int rank = 0;
        for (int j = 0; j < n; ++j) rank += (carr[j] < my) ? 1 : 0;
        if (rank < R) {                                     // keys distinct (idx bits)
            const int tt = b * F + (int)(uint32_t)my;
            flag[tt] = 1;
#pragma unroll
            for (int j = 0; j < 3; ++j) {
                const int nb   = adj[(size_t)tt * 3 + j];
                const int tgt  = b * F + nb;
                const int slot = atomicAdd(&cnt[tgt], 1);
                if (slot < CAP) srcs[(size_t)tgt * CAP + slot] = tt;
            }
        }
    }
}

// ---------------------------------------------------------------------------
// kFL: 256 blocks, full GPU width (round-2 lesson: scatter needs width;
// round-3 lesson: no ticket/fence). Now a PURE wide scatter: bin < T ->
// flag + push. Boundary bin handled entirely by kHT. No LDS, 1 barrier-free
// body.
// ---------------------------------------------------------------------------
__global__ __launch_bounds__(256) void kFL(const float* __restrict__ w,
                                           const int* __restrict__ adj,
                                           const unsigned int* __restrict__ lsb,
                                           const int* __restrict__ tbin,
                                           int* __restrict__ flag,
                                           int* __restrict__ cnt,
                                           int* __restrict__ srcs) {
    const int t = blockIdx.x * 256 + threadIdx.x;           // [0, B*F)
    const int b = t >> 13;                                  // block spans one batch
    const float lo    = __uint_as_float(lsb[b * 2 + 0]);
    const float hi    = __uint_as_float(lsb[b * 2 + 1]);
    const float scale = (float)(NB - 2) / fmaxf(hi - lo, 1e-30f);

    const float v = w[t];
    if (binOf(v, lo, scale) < tbin[b]) {
        flag[t] = 1;
#pragma unroll
        for (int j = 0; j < 3; ++j) {
            const int n    = adj[(size_t)t * 3 + j];
            const int tgt  = b * F + n;
            const int slot = atomicAdd(&cnt[tgt], 1);
            if (slot < CAP) srcs[(size_t)tgt * CAP + slot] = t;
        }
    }
}

// ---------------------------------------------------------------------------
// kG: one wave per face — fused merge + normalize + erase. NEW: non-temporal
// stores for `out` (64 MB streaming, zero reuse) keep L2/L3 for feat rows
// (re-read as sources; warmed by kW this iteration).
// ---------------------------------------------------------------------------
__global__ __launch_bounds__(256) void kG(const float* __restrict__ feat,
                                          const int* __restrict__ cnt,
                                          const int* __restrict__ flag,
                                          const int* __restrict__ srcs,
                                          float* __restrict__ out) {
    const int b     = blockIdx.x & 7;                       // batch == XCD
    const int inner = blockIdx.x >> 3;
    const int wid   = b * F + inner * 4 + (threadIdx.x >> 6);
    const int lane  = threadIdx.x & 63;
    f32x4* drow = (f32x4*)(out + (size_t)wid * C);

    if (flag[wid]) {                                        // wave-uniform branch
        f32x4 z = {0.f, 0.f, 0.f, 0.f};
        __builtin_nontemporal_store(z, &drow[lane]);
        return;
    }
    const int m  = cnt[wid];
    const int mm = m < CAP ? m : CAP;

    const int sidx = (lane < CAP) ? srcs[(size_t)wid * CAP + lane] : 0;

    float4 acc = ((const float4*)(feat + (size_t)wid * C))[lane];
    const float inv3 = 1.0f / 3.0f;
    for (int i = 0; i < mm; ++i) {
        const int s = __shfl(sidx, i, 64);
        const float4 v = ((const float4*)(feat + (size_t)s * C))[lane];
        acc.x += v.x * inv3; acc.y += v.y * inv3;
        acc.z += v.z * inv3; acc.w += v.w * inv3;
    }
    const float inv = 1.0f / (1.0f + (float)m);
    f32x4 r;
    r.x = acc.x * inv; r.y = acc.y * inv;
    r.z = acc.z * inv; r.w = acc.w * inv;
    __builtin_nontemporal_store(r, &drow[lane]);
}

extern "C" void kernel_launch(void* const* d_in, const int* in_sizes, int n_in,
                              void* d_out, int out_size, void* d_ws, size_t ws_size,
                              hipStream_t stream) {
    const float* feat = (const float*)d_in[0];
    const int*   adj  = (const int*)d_in[1];
    const int*   ring = (const int*)d_in[2];
    float* out = (float*)d_out;

    // ws layout: w | cnt | flag | srcs | tbin | lsb
    float* w    = (float*)d_ws;                             // B*F
    int*   cnt  = (int*)(w + BF);                           // B*F
    int*   flag = cnt + BF;                                 // B*F
    int*   srcs = flag + BF;                                // B*F*CAP (4 MiB)
    int*   tbin = srcs + (size_t)BF * CAP;                  // B
    unsigned int* lsb = (unsigned int*)(tbin + B);          // 2*B

    kW  <<<BF / 4, 256, 0, stream>>>(feat, ring, w, cnt, flag);
    kHT <<<B, 1024, 0, stream>>>(w, adj, tbin, lsb, flag, cnt, srcs);
    kFL <<<BF / 256, 256, 0, stream>>>(w, adj, lsb, tbin, flag, cnt, srcs);
    kG  <<<BF / 4, 256, 0, stream>>>(feat, cnt, flag, srcs, out);
}